// Round 3
// baseline (831.332 us; speedup 1.0000x reference)
//
#include <hip/hip_runtime.h>
#include <math.h>

// ---------------------------------------------------------------------------
// 2-layer GCN (PyG GCNConv) on MI355X — bucketed-CSR gather version.
// out[i] = logsoftmax( dinv[i]*(g2[i] + sum_{e:dst=i} g2[src_e]) + b2 )
// g2 = dinv*( relu( dinv*(g1[i]+sum g1[src]) + b1 ) @ W2 ), g1 = (x@W1)*dinv
// Counting sort done in two passes (bucket by dst>>5, then place within
// bucket via LDS cursors) so scattered writes stay in cache-resident regions.
// ---------------------------------------------------------------------------

#define F_IN   128
#define F_HID  32
#define F_OUT  7
#define SCAN_B 512
#define NPB_SHIFT 5           // 32 nodes per bucket
#define NPB (1 << NPB_SHIFT)

// --- Pass A: bucket histogram ---
__global__ void k_bucketHist(const int* __restrict__ dst, int E, int* __restrict__ hist) {
    int e = blockIdx.x * blockDim.x + threadIdx.x;
    if (e < E) atomicAdd(&hist[dst[e] >> NPB_SHIFT], 1);
}

// exclusive scan of NB (<=4096) bucket counts; one block of 1024 threads.
__global__ void k_scanBuckets(const int* __restrict__ hist, int NB,
                              int* __restrict__ bucketStart, int* __restrict__ bucketCursor) {
    __shared__ int s[1024];
    int t = threadIdx.x;
    int v[4];
    int base = t * 4;
    int sum = 0;
    #pragma unroll
    for (int k = 0; k < 4; ++k) { v[k] = (base + k < NB) ? hist[base + k] : 0; sum += v[k]; }
    s[t] = sum;
    __syncthreads();
    for (int off = 1; off < 1024; off <<= 1) {
        int a = (t >= off) ? s[t - off] : 0;
        __syncthreads();
        s[t] += a;
        __syncthreads();
    }
    int ex = s[t] - sum;
    #pragma unroll
    for (int k = 0; k < 4; ++k) {
        if (base + k < NB) { bucketStart[base + k] = ex; bucketCursor[base + k] = ex; }
        ex += v[k];
    }
}

// scatter (local5|src17) packed ints to bucket-major pairBuf.
__global__ void k_bucketFill(const int* __restrict__ src, const int* __restrict__ dst,
                             int E, int* __restrict__ bucketCursor, int* __restrict__ pairBuf) {
    int e = blockIdx.x * blockDim.x + threadIdx.x;
    if (e < E) {
        int s = src[e], d = dst[e];
        int b = d >> NPB_SHIFT;
        int pos = atomicAdd(&bucketCursor[b], 1);
        pairBuf[pos] = ((d & (NPB - 1)) << 17) | s;   // src < 2^17
    }
}

// per-bucket LDS histogram -> degi (replaces 3.2M random global atomics).
__global__ void k_bucketDeg(const int* __restrict__ pairBuf, const int* __restrict__ bucketStart,
                            const int* __restrict__ bucketCursor, int* __restrict__ degi, int n) {
    __shared__ int cnt[NPB];
    int b = blockIdx.x;
    int t = threadIdx.x;
    if (t < NPB) cnt[t] = 0;
    __syncthreads();
    int bs = bucketStart[b], be = bucketCursor[b];
    for (int j = bs + t; j < be; j += blockDim.x)
        atomicAdd(&cnt[pairBuf[j] >> 17], 1);
    __syncthreads();
    int node = (b << NPB_SHIFT) + t;
    if (t < NPB && node < n) degi[node] = cnt[t];
}

__global__ void k_dinv(const int* __restrict__ degi, float* __restrict__ dinv, int n) {
    int i = blockIdx.x * blockDim.x + threadIdx.x;
    if (i < n) dinv[i] = rsqrtf((float)degi[i] + 1.0f);  // +1 self-loop
}

// --- node-offset scan (3 kernels, all parallel) ---
__global__ void k_scan1(const int* __restrict__ degi, int n, int* __restrict__ bsum) {
    __shared__ int s[SCAN_B];
    int t = threadIdx.x;
    int idx = blockIdx.x * SCAN_B + t;
    s[t] = (idx < n) ? degi[idx] : 0;
    __syncthreads();
    for (int off = SCAN_B / 2; off > 0; off >>= 1) {
        if (t < off) s[t] += s[t + off];
        __syncthreads();
    }
    if (t == 0) bsum[blockIdx.x] = s[0];
}

__global__ void k_scan2p(int* __restrict__ bsum, int nb) {  // nb <= 256
    __shared__ int s[256];
    int t = threadIdx.x;
    int v = (t < nb) ? bsum[t] : 0;
    s[t] = v;
    __syncthreads();
    for (int off = 1; off < 256; off <<= 1) {
        int a = (t >= off) ? s[t - off] : 0;
        __syncthreads();
        s[t] += a;
        __syncthreads();
    }
    if (t < nb) bsum[t] = s[t] - v;
}

__global__ void k_scan3(const int* __restrict__ degi, const int* __restrict__ bsum,
                        int n, int* __restrict__ cursor) {
    __shared__ int s[SCAN_B];
    int t = threadIdx.x;
    int idx = blockIdx.x * SCAN_B + t;
    int v = (idx < n) ? degi[idx] : 0;
    s[t] = v;
    __syncthreads();
    for (int off = 1; off < SCAN_B; off <<= 1) {
        int add = (t >= off) ? s[t - off] : 0;
        __syncthreads();
        s[t] += add;
        __syncthreads();
    }
    if (idx < n) cursor[idx] = bsum[blockIdx.x] + s[t] - v;  // exclusive -> start offset
}

// per-bucket placement with LDS cursors; srcSorted writes hit a ~4KB region.
__global__ void k_bucketPlace(const int* __restrict__ pairBuf, const int* __restrict__ bucketStart,
                              const int* __restrict__ bucketCursor, const int* __restrict__ cursor,
                              int* __restrict__ srcSorted, int n) {
    __shared__ int cur[NPB];
    int b = blockIdx.x;
    int t = threadIdx.x;
    int nodeBase = b << NPB_SHIFT;
    if (t < NPB) cur[t] = (nodeBase + t < n) ? cursor[nodeBase + t] : 0;
    __syncthreads();
    int bs = bucketStart[b], be = bucketCursor[b];
    for (int j = bs + t; j < be; j += blockDim.x) {
        int p = pairBuf[j];
        int local = p >> 17;
        int s = p & 0x1FFFF;
        int pos = atomicAdd(&cur[local], 1);
        srcSorted[pos] = s;
    }
}

// GEMM1: g1[i][f] = dinv[i] * sum_k x[i][k]*W1[k][f].
__global__ void k_gemm1(const float* __restrict__ x, const float* __restrict__ W1,
                        const float* __restrict__ dinv, float* __restrict__ g1, int n) {
    __shared__ float sW[F_IN * F_HID];
    __shared__ float sx[8][F_IN];
    int t = threadIdx.x;
    for (int i = t; i < F_IN * F_HID; i += 256) sW[i] = W1[i];
    int row0 = blockIdx.x * 8;
    for (int i = t; i < 8 * F_IN; i += 256) {
        int r = i >> 7, c = i & 127;
        int gr = row0 + r;
        sx[r][c] = (gr < n) ? x[(long long)gr * F_IN + c] : 0.0f;
    }
    __syncthreads();
    int r = t >> 5;
    int f = t & 31;
    int gr = row0 + r;
    if (gr < n) {
        float acc = 0.0f;
        #pragma unroll
        for (int k = 0; k < F_IN; ++k) acc += sx[r][k] * sW[k * F_HID + f];
        g1[gr * F_HID + f] = acc * dinv[gr];
    }
}

// Gather conv1 + ReLU + tiny GEMM2 fused. 32 lanes/node, 8 nodes/block.
__global__ void k_gather1l2(const float* __restrict__ g1, const int* __restrict__ srcSorted,
                            const int* __restrict__ cursor, const int* __restrict__ degi,
                            const float* __restrict__ dinv, const float* __restrict__ b1,
                            const float* __restrict__ W2, float* __restrict__ g2p, int n) {
    int t = threadIdx.x;
    int lane = t & 31;
    int node = blockIdx.x * 8 + (t >> 5);
    if (node >= n) return;
    float w2r[F_OUT];
    #pragma unroll
    for (int c = 0; c < F_OUT; ++c) w2r[c] = W2[lane * F_OUT + c];
    int start = cursor[node];
    int end = start + degi[node];
    float acc = g1[node * F_HID + lane];  // self-loop init
    for (int j = start; j < end; ++j) {
        int s = srcSorted[j];             // broadcast across the 32-lane group
        acc += g1[s * F_HID + lane];      // 128B coalesced line per group
    }
    float di = dinv[node];
    float h = di * acc + b1[lane];
    h = h > 0.0f ? h : 0.0f;
    float p0 = h * w2r[0], p1 = h * w2r[1], p2 = h * w2r[2], p3 = h * w2r[3];
    float p4 = h * w2r[4], p5 = h * w2r[5], p6 = h * w2r[6];
    #pragma unroll
    for (int m = 1; m < 32; m <<= 1) {
        p0 += __shfl_xor(p0, m, 64);
        p1 += __shfl_xor(p1, m, 64);
        p2 += __shfl_xor(p2, m, 64);
        p3 += __shfl_xor(p3, m, 64);
        p4 += __shfl_xor(p4, m, 64);
        p5 += __shfl_xor(p5, m, 64);
        p6 += __shfl_xor(p6, m, 64);
    }
    if (lane == 0) {
        float4 q0 = make_float4(di * p0, di * p1, di * p2, di * p3);
        float4 q1 = make_float4(di * p4, di * p5, di * p6, 0.0f);
        *(float4*)&g2p[node * 8]     = q0;
        *(float4*)&g2p[node * 8 + 4] = q1;
    }
}

// Gather conv2 + bias + log-softmax fused. 8 lanes/node, 32 nodes/block.
__global__ void k_gather2final(const float* __restrict__ g2p, const int* __restrict__ srcSorted,
                               const int* __restrict__ cursor, const int* __restrict__ degi,
                               const float* __restrict__ dinv, const float* __restrict__ b2,
                               float* __restrict__ out, int n) {
    int t = threadIdx.x;
    int c = t & 7;
    int node = blockIdx.x * 32 + (t >> 3);
    if (node >= n) return;
    int start = cursor[node];
    int end = start + degi[node];
    float acc = g2p[node * 8 + c];        // self-loop init (pad col = 0)
    for (int j = start; j < end; ++j) {
        int s = srcSorted[j];
        acc += g2p[s * 8 + c];            // 32B aligned chunk per group
    }
    float v = dinv[node] * acc + ((c < F_OUT) ? b2[c] : -1e30f);
    float m = v;
    #pragma unroll
    for (int msk = 1; msk < 8; msk <<= 1) m = fmaxf(m, __shfl_xor(m, msk, 64));
    float ex = __expf(v - m);
    float ssum = ex;
    #pragma unroll
    for (int msk = 1; msk < 8; msk <<= 1) ssum += __shfl_xor(ssum, msk, 64);
    float ls = __logf(ssum) + m;
    if (c < F_OUT) out[node * F_OUT + c] = v - ls;
}

extern "C" void kernel_launch(void* const* d_in, const int* in_sizes, int n_in,
                              void* d_out, int out_size, void* d_ws, size_t ws_size,
                              hipStream_t stream) {
    const float* x  = (const float*)d_in[0];
    const int*   ei = (const int*)d_in[1];
    const float* W1 = (const float*)d_in[2];
    const float* b1 = (const float*)d_in[3];
    const float* W2 = (const float*)d_in[4];
    const float* b2 = (const float*)d_in[5];
    float* out = (float*)d_out;

    int n = in_sizes[0] / F_IN;   // 100000
    int E = in_sizes[1] / 2;      // 3200000
    const int* src = ei;
    const int* dst = ei + E;
    int NB = (n + NPB - 1) >> NPB_SHIFT;       // 3125 buckets
    int nb = (n + SCAN_B - 1) / SCAN_B;        // 196 scan blocks

    // workspace layout (g1 aliases pairBuf: pairBuf dead after k_bucketPlace)
    int*   degi         = (int*)d_ws;                   // [n]
    int*   cursor       = degi + n;                     // [n]
    float* dinv         = (float*)(cursor + n);         // [n]
    int*   srcSorted    = (int*)(dinv + n);             // [E]
    int*   pairBuf      = srcSorted + E;                // [E]  (reused as g1)
    float* g1           = (float*)pairBuf;              // [n*32] == E floats
    float* g2p          = (float*)(pairBuf + E);        // [n*8]
    int*   hist         = (int*)(g2p + (size_t)n * 8);  // [NB]
    int*   bucketStart  = hist + NB;                    // [NB]
    int*   bucketCursor = bucketStart + NB;             // [NB]
    int*   bsum         = bucketCursor + NB;            // [nb]

    hipMemsetAsync(hist, 0, (size_t)NB * sizeof(int), stream);

    k_bucketHist<<<(E + 255) / 256, 256, 0, stream>>>(dst, E, hist);
    k_scanBuckets<<<1, 1024, 0, stream>>>(hist, NB, bucketStart, bucketCursor);
    k_bucketFill<<<(E + 255) / 256, 256, 0, stream>>>(src, dst, E, bucketCursor, pairBuf);
    k_bucketDeg<<<NB, 256, 0, stream>>>(pairBuf, bucketStart, bucketCursor, degi, n);
    k_dinv<<<(n + 255) / 256, 256, 0, stream>>>(degi, dinv, n);
    k_scan1<<<nb, SCAN_B, 0, stream>>>(degi, n, bsum);
    k_scan2p<<<1, 256, 0, stream>>>(bsum, nb);
    k_scan3<<<nb, SCAN_B, 0, stream>>>(degi, bsum, n, cursor);
    k_bucketPlace<<<NB, 256, 0, stream>>>(pairBuf, bucketStart, bucketCursor, cursor, srcSorted, n);
    k_gemm1<<<(n + 7) / 8, 256, 0, stream>>>(x, W1, dinv, g1, n);
    k_gather1l2<<<(n + 7) / 8, 256, 0, stream>>>(g1, srcSorted, cursor, degi, dinv, b1, W2, g2p, n);
    k_gather2final<<<(n + 31) / 32, 256, 0, stream>>>(g2p, srcSorted, cursor, degi, dinv, b2, out, n);
}

// Round 4
// 326.621 us; speedup vs baseline: 2.5452x; 2.5452x over previous
//
#include <hip/hip_runtime.h>
#include <math.h>

// ---------------------------------------------------------------------------
// 2-layer GCN (PyG GCNConv) on MI355X — tiled-partition CSR gather version.
// out[i] = logsoftmax( dinv[i]*(g2[i] + sum_{e:dst=i} g2[src_e]) + b2 )
// g2 = dinv*( relu( dinv*(g1[i]+sum g1[src]) + b1 ) @ W2 ), g1 = (x@W1)*dinv
// CSR built by two-pass tiled counting sort: per-(tile,bucket) pre-scanned
// contiguous output runs -> no global atomics, no write amplification.
// ---------------------------------------------------------------------------

#define F_IN   128
#define F_HID  32
#define F_OUT  7
#define TILE   4096
#define BSH    9              // 512 nodes per bucket
#define BNODES 512

// Pass A: per-tile histogram over NB buckets. counts is tile-major [NT][NB].
__global__ void k_tileHist(const int* __restrict__ dst, int E, int NB,
                           int* __restrict__ counts) {
    __shared__ int h[BNODES];
    int tile = blockIdx.x, t = threadIdx.x;
    for (int i = t; i < NB; i += 256) h[i] = 0;
    __syncthreads();
    int base = tile * TILE;
    int lim = base + TILE; if (lim > E) lim = E;
    for (int i = base + t; i < lim; i += 256) atomicAdd(&h[dst[i] >> BSH], 1);
    __syncthreads();
    for (int i = t; i < NB; i += 256) counts[tile * NB + i] = h[i];
}

// Exclusive scan of counts in BUCKET-MAJOR order (idx = b*NT + t).
__global__ void k_scanA(const int* __restrict__ counts, int NSCAN, int NB, int NT,
                        int* __restrict__ bsum) {
    __shared__ int s[1024];
    int t = threadIdx.x;
    int idx = blockIdx.x * 1024 + t;
    int v = 0;
    if (idx < NSCAN) { int b = idx / NT, tt = idx - b * NT; v = counts[tt * NB + b]; }
    s[t] = v;
    __syncthreads();
    for (int off = 512; off > 0; off >>= 1) {
        if (t < off) s[t] += s[t + off];
        __syncthreads();
    }
    if (t == 0) bsum[blockIdx.x] = s[0];
}

__global__ void k_scanB(int* __restrict__ bsum, int nb) {  // nb <= 1024
    __shared__ int s[1024];
    int t = threadIdx.x;
    int v = (t < nb) ? bsum[t] : 0;
    s[t] = v;
    __syncthreads();
    for (int off = 1; off < 1024; off <<= 1) {
        int a = (t >= off) ? s[t - off] : 0;
        __syncthreads();
        s[t] += a;
        __syncthreads();
    }
    if (t < nb) bsum[t] = s[t] - v;
}

__global__ void k_scanC(const int* __restrict__ counts, int NSCAN, int NB, int NT,
                        const int* __restrict__ bsum, int* __restrict__ tileOffset) {
    __shared__ int s[1024];
    int t = threadIdx.x;
    int idx = blockIdx.x * 1024 + t;
    int v = 0;
    if (idx < NSCAN) { int b = idx / NT, tt = idx - b * NT; v = counts[tt * NB + b]; }
    s[t] = v;
    __syncthreads();
    for (int off = 1; off < 1024; off <<= 1) {
        int a = (t >= off) ? s[t - off] : 0;
        __syncthreads();
        s[t] += a;
        __syncthreads();
    }
    if (idx < NSCAN) tileOffset[idx] = bsum[blockIdx.x] + s[t] - v;  // bucket-major linear
}

// Pass B: scatter packed (local9|src17) into per-(tile,bucket) contiguous runs.
__global__ void k_tileFill(const int* __restrict__ src, const int* __restrict__ dst,
                           int E, int NB, int NT, const int* __restrict__ tileOffset,
                           int* __restrict__ pairBuf) {
    __shared__ int lcur[BNODES];
    int tile = blockIdx.x, t = threadIdx.x;
    for (int i = t; i < NB; i += 256) lcur[i] = tileOffset[i * NT + tile];
    __syncthreads();
    int base = tile * TILE;
    int lim = base + TILE; if (lim > E) lim = E;
    for (int i = base + t; i < lim; i += 256) {
        int s = src[i], d = dst[i];
        int b = d >> BSH;
        int pos = atomicAdd(&lcur[b], 1);             // LDS cursor, run is tile-private
        pairBuf[pos] = ((d & (BNODES - 1)) << 17) | s; // src < 2^17
    }
}

// Pass C: per-bucket CSR finish — degi/cursor/dinv + srcSorted placement.
__global__ void k_bucketCSR(const int* __restrict__ pairBuf, const int* __restrict__ tileOffset,
                            int NT, int NB, int E, int n,
                            int* __restrict__ degi, int* __restrict__ cursor,
                            float* __restrict__ dinv, int* __restrict__ srcSorted) {
    __shared__ int cnt[BNODES];
    __shared__ int pref[BNODES];
    int b = blockIdx.x, t = threadIdx.x;
    cnt[t] = 0;
    __syncthreads();
    int bs = tileOffset[b * NT];
    int be = (b + 1 < NB) ? tileOffset[(b + 1) * NT] : E;
    for (int j = bs + t; j < be; j += BNODES) atomicAdd(&cnt[pairBuf[j] >> 17], 1);
    __syncthreads();
    int v = cnt[t];
    pref[t] = v;
    __syncthreads();
    for (int off = 1; off < BNODES; off <<= 1) {
        int a = (t >= off) ? pref[t - off] : 0;
        __syncthreads();
        pref[t] += a;
        __syncthreads();
    }
    int ex = pref[t] - v;                 // exclusive prefix within bucket
    int node = (b << BSH) + t;
    if (node < n) {
        degi[node]   = v;
        cursor[node] = bs + ex;
        dinv[node]   = rsqrtf((float)v + 1.0f);  // +1 self-loop
    }
    __syncthreads();
    cnt[t] = bs + ex;                     // reuse as placement cursors
    __syncthreads();
    for (int j = bs + t; j < be; j += BNODES) {
        int p = pairBuf[j];
        int pos = atomicAdd(&cnt[p >> 17], 1);
        srcSorted[pos] = p & 0x1FFFF;     // writes confined to bucket's ~65KB region
    }
}

// GEMM1: g1[i][f] = dinv[i] * sum_k x[i][k]*W1[k][f].
__global__ void k_gemm1(const float* __restrict__ x, const float* __restrict__ W1,
                        const float* __restrict__ dinv, float* __restrict__ g1, int n) {
    __shared__ float sW[F_IN * F_HID];
    __shared__ float sx[8][F_IN];
    int t = threadIdx.x;
    for (int i = t; i < F_IN * F_HID; i += 256) sW[i] = W1[i];
    int row0 = blockIdx.x * 8;
    for (int i = t; i < 8 * F_IN; i += 256) {
        int r = i >> 7, c = i & 127;
        int gr = row0 + r;
        sx[r][c] = (gr < n) ? x[(long long)gr * F_IN + c] : 0.0f;
    }
    __syncthreads();
    int r = t >> 5;
    int f = t & 31;
    int gr = row0 + r;
    if (gr < n) {
        float acc = 0.0f;
        #pragma unroll
        for (int k = 0; k < F_IN; ++k) acc += sx[r][k] * sW[k * F_HID + f];
        g1[gr * F_HID + f] = acc * dinv[gr];
    }
}

// Gather conv1 + ReLU + tiny GEMM2 fused. 32 lanes/node, 8 nodes/block.
__global__ void k_gather1l2(const float* __restrict__ g1, const int* __restrict__ srcSorted,
                            const int* __restrict__ cursor, const int* __restrict__ degi,
                            const float* __restrict__ dinv, const float* __restrict__ b1,
                            const float* __restrict__ W2, float* __restrict__ g2p, int n) {
    int t = threadIdx.x;
    int lane = t & 31;
    int node = blockIdx.x * 8 + (t >> 5);
    if (node >= n) return;
    float w2r[F_OUT];
    #pragma unroll
    for (int c = 0; c < F_OUT; ++c) w2r[c] = W2[lane * F_OUT + c];
    int start = cursor[node];
    int end = start + degi[node];
    float acc = g1[node * F_HID + lane];  // self-loop init
    for (int j = start; j < end; ++j) {
        int s = srcSorted[j];             // broadcast across the 32-lane group
        acc += g1[s * F_HID + lane];      // 128B coalesced line per group
    }
    float di = dinv[node];
    float h = di * acc + b1[lane];
    h = h > 0.0f ? h : 0.0f;
    float p0 = h * w2r[0], p1 = h * w2r[1], p2 = h * w2r[2], p3 = h * w2r[3];
    float p4 = h * w2r[4], p5 = h * w2r[5], p6 = h * w2r[6];
    #pragma unroll
    for (int m = 1; m < 32; m <<= 1) {
        p0 += __shfl_xor(p0, m, 64);
        p1 += __shfl_xor(p1, m, 64);
        p2 += __shfl_xor(p2, m, 64);
        p3 += __shfl_xor(p3, m, 64);
        p4 += __shfl_xor(p4, m, 64);
        p5 += __shfl_xor(p5, m, 64);
        p6 += __shfl_xor(p6, m, 64);
    }
    if (lane == 0) {
        float4 q0 = make_float4(di * p0, di * p1, di * p2, di * p3);
        float4 q1 = make_float4(di * p4, di * p5, di * p6, 0.0f);
        *(float4*)&g2p[node * 8]     = q0;
        *(float4*)&g2p[node * 8 + 4] = q1;
    }
}

// Gather conv2 + bias + log-softmax fused. 8 lanes/node, 32 nodes/block.
__global__ void k_gather2final(const float* __restrict__ g2p, const int* __restrict__ srcSorted,
                               const int* __restrict__ cursor, const int* __restrict__ degi,
                               const float* __restrict__ dinv, const float* __restrict__ b2,
                               float* __restrict__ out, int n) {
    int t = threadIdx.x;
    int c = t & 7;
    int node = blockIdx.x * 32 + (t >> 3);
    if (node >= n) return;
    int start = cursor[node];
    int end = start + degi[node];
    float acc = g2p[node * 8 + c];        // self-loop init (pad col = 0)
    for (int j = start; j < end; ++j) {
        int s = srcSorted[j];
        acc += g2p[s * 8 + c];            // 32B aligned chunk per group
    }
    float v = dinv[node] * acc + ((c < F_OUT) ? b2[c] : -1e30f);
    float m = v;
    #pragma unroll
    for (int msk = 1; msk < 8; msk <<= 1) m = fmaxf(m, __shfl_xor(m, msk, 64));
    float ex = __expf(v - m);
    float ssum = ex;
    #pragma unroll
    for (int msk = 1; msk < 8; msk <<= 1) ssum += __shfl_xor(ssum, msk, 64);
    float ls = __logf(ssum) + m;
    if (c < F_OUT) out[node * F_OUT + c] = v - ls;
}

extern "C" void kernel_launch(void* const* d_in, const int* in_sizes, int n_in,
                              void* d_out, int out_size, void* d_ws, size_t ws_size,
                              hipStream_t stream) {
    const float* x  = (const float*)d_in[0];
    const int*   ei = (const int*)d_in[1];
    const float* W1 = (const float*)d_in[2];
    const float* b1 = (const float*)d_in[3];
    const float* W2 = (const float*)d_in[4];
    const float* b2 = (const float*)d_in[5];
    float* out = (float*)d_out;

    int n = in_sizes[0] / F_IN;            // 100000
    int E = in_sizes[1] / 2;               // 3200000
    const int* src = ei;
    const int* dst = ei + E;
    int NB = (n + BNODES - 1) >> BSH;      // 196 buckets
    int NT = (E + TILE - 1) / TILE;        // 782 tiles
    int NSCAN = NB * NT;                   // 153272
    int nsb = (NSCAN + 1023) / 1024;       // 150 scan blocks

    // workspace layout (g1 aliases pairBuf: pairBuf dead after k_bucketCSR)
    int*   degi       = (int*)d_ws;                  // [n]
    int*   cursor     = degi + n;                    // [n]
    float* dinv       = (float*)(cursor + n);        // [n]
    int*   srcSorted  = (int*)(dinv + n);            // [E]
    int*   pairBuf    = srcSorted + E;               // [E]  (reused as g1)
    float* g1         = (float*)pairBuf;             // [n*32] == E floats
    float* g2p        = (float*)(pairBuf + E);       // [n*8]
    int*   counts     = (int*)(g2p + (size_t)n * 8); // [NSCAN] tile-major
    int*   tileOffset = counts + NSCAN;              // [NSCAN] bucket-major
    int*   bsum       = tileOffset + NSCAN;          // [nsb]

    k_tileHist<<<NT, 256, 0, stream>>>(dst, E, NB, counts);
    k_scanA<<<nsb, 1024, 0, stream>>>(counts, NSCAN, NB, NT, bsum);
    k_scanB<<<1, 1024, 0, stream>>>(bsum, nsb);
    k_scanC<<<nsb, 1024, 0, stream>>>(counts, NSCAN, NB, NT, bsum, tileOffset);
    k_tileFill<<<NT, 256, 0, stream>>>(src, dst, E, NB, NT, tileOffset, pairBuf);
    k_bucketCSR<<<NB, BNODES, 0, stream>>>(pairBuf, tileOffset, NT, NB, E, n,
                                           degi, cursor, dinv, srcSorted);
    k_gemm1<<<(n + 7) / 8, 256, 0, stream>>>(x, W1, dinv, g1, n);
    k_gather1l2<<<(n + 7) / 8, 256, 0, stream>>>(g1, srcSorted, cursor, degi, dinv, b1, W2, g2p, n);
    k_gather2final<<<(n + 31) / 32, 256, 0, stream>>>(g2p, srcSorted, cursor, degi, dinv, b2, out, n);
}

// Round 5
// 205.862 us; speedup vs baseline: 4.0383x; 1.5866x over previous
//
#include <hip/hip_runtime.h>
#include <math.h>

// ---------------------------------------------------------------------------
// 2-layer GCN (PyG GCNConv) on MI355X — tiled-partition CSR + MLP-deep gather.
// out[i] = logsoftmax( dinv[i]*(g2[i] + sum_{e:dst=i} g2[src_e]) + b2 )
// g2 = dinv*( relu( dinv*(g1[i]+sum g1[src]) + b1 ) @ W2 ), g1 = (x@W1)*dinv
// Gathers use 8 lanes/node, float4 rows, 4-edge unroll w/ 4 accumulators
// (32 concurrent gather streams per wave) to cover L2/L3 latency.
// ---------------------------------------------------------------------------

#define F_IN   128
#define F_HID  32
#define F_OUT  7
#define TILE   4096
#define BSH    9              // 512 nodes per bucket
#define BNODES 512

__device__ __forceinline__ float4 f4add(float4 a, float4 b) {
    return make_float4(a.x + b.x, a.y + b.y, a.z + b.z, a.w + b.w);
}

// Pass A: per-tile histogram over NB buckets. counts is tile-major [NT][NB].
__global__ void k_tileHist(const int* __restrict__ dst, int E, int NB,
                           int* __restrict__ counts) {
    __shared__ int h[BNODES];
    int tile = blockIdx.x, t = threadIdx.x;
    for (int i = t; i < NB; i += 256) h[i] = 0;
    __syncthreads();
    int base = tile * TILE;
    int lim = base + TILE; if (lim > E) lim = E;
    for (int i = base + t; i < lim; i += 256) atomicAdd(&h[dst[i] >> BSH], 1);
    __syncthreads();
    for (int i = t; i < NB; i += 256) counts[tile * NB + i] = h[i];
}

// Exclusive scan of counts in BUCKET-MAJOR order (idx = b*NT + t).
__global__ void k_scanA(const int* __restrict__ counts, int NSCAN, int NB, int NT,
                        int* __restrict__ bsum) {
    __shared__ int s[1024];
    int t = threadIdx.x;
    int idx = blockIdx.x * 1024 + t;
    int v = 0;
    if (idx < NSCAN) { int b = idx / NT, tt = idx - b * NT; v = counts[tt * NB + b]; }
    s[t] = v;
    __syncthreads();
    for (int off = 512; off > 0; off >>= 1) {
        if (t < off) s[t] += s[t + off];
        __syncthreads();
    }
    if (t == 0) bsum[blockIdx.x] = s[0];
}

__global__ void k_scanB(int* __restrict__ bsum, int nb) {  // nb <= 1024
    __shared__ int s[1024];
    int t = threadIdx.x;
    int v = (t < nb) ? bsum[t] : 0;
    s[t] = v;
    __syncthreads();
    for (int off = 1; off < 1024; off <<= 1) {
        int a = (t >= off) ? s[t - off] : 0;
        __syncthreads();
        s[t] += a;
        __syncthreads();
    }
    if (t < nb) bsum[t] = s[t] - v;
}

__global__ void k_scanC(const int* __restrict__ counts, int NSCAN, int NB, int NT,
                        const int* __restrict__ bsum, int* __restrict__ tileOffset) {
    __shared__ int s[1024];
    int t = threadIdx.x;
    int idx = blockIdx.x * 1024 + t;
    int v = 0;
    if (idx < NSCAN) { int b = idx / NT, tt = idx - b * NT; v = counts[tt * NB + b]; }
    s[t] = v;
    __syncthreads();
    for (int off = 1; off < 1024; off <<= 1) {
        int a = (t >= off) ? s[t - off] : 0;
        __syncthreads();
        s[t] += a;
        __syncthreads();
    }
    if (idx < NSCAN) tileOffset[idx] = bsum[blockIdx.x] + s[t] - v;  // bucket-major linear
}

// Pass B: scatter packed (local9|src17) into per-(tile,bucket) contiguous runs.
__global__ void k_tileFill(const int* __restrict__ src, const int* __restrict__ dst,
                           int E, int NB, int NT, const int* __restrict__ tileOffset,
                           int* __restrict__ pairBuf) {
    __shared__ int lcur[BNODES];
    int tile = blockIdx.x, t = threadIdx.x;
    for (int i = t; i < NB; i += 256) lcur[i] = tileOffset[i * NT + tile];
    __syncthreads();
    int base = tile * TILE;
    int lim = base + TILE; if (lim > E) lim = E;
    for (int i = base + t; i < lim; i += 256) {
        int s = src[i], d = dst[i];
        int b = d >> BSH;
        int pos = atomicAdd(&lcur[b], 1);              // LDS cursor, run is tile-private
        pairBuf[pos] = ((d & (BNODES - 1)) << 17) | s; // src < 2^17
    }
}

// Pass C: per-bucket CSR finish — degi/cursor/dinv + srcSorted placement.
__global__ void k_bucketCSR(const int* __restrict__ pairBuf, const int* __restrict__ tileOffset,
                            int NT, int NB, int E, int n,
                            int* __restrict__ degi, int* __restrict__ cursor,
                            float* __restrict__ dinv, int* __restrict__ srcSorted) {
    __shared__ int cnt[BNODES];
    __shared__ int pref[BNODES];
    int b = blockIdx.x, t = threadIdx.x;
    cnt[t] = 0;
    __syncthreads();
    int bs = tileOffset[b * NT];
    int be = (b + 1 < NB) ? tileOffset[(b + 1) * NT] : E;
    for (int j = bs + t; j < be; j += BNODES) atomicAdd(&cnt[pairBuf[j] >> 17], 1);
    __syncthreads();
    int v = cnt[t];
    pref[t] = v;
    __syncthreads();
    for (int off = 1; off < BNODES; off <<= 1) {
        int a = (t >= off) ? pref[t - off] : 0;
        __syncthreads();
        pref[t] += a;
        __syncthreads();
    }
    int ex = pref[t] - v;                 // exclusive prefix within bucket
    int node = (b << BSH) + t;
    if (node < n) {
        degi[node]   = v;
        cursor[node] = bs + ex;
        dinv[node]   = rsqrtf((float)v + 1.0f);  // +1 self-loop
    }
    __syncthreads();
    cnt[t] = bs + ex;                     // reuse as placement cursors
    __syncthreads();
    for (int j = bs + t; j < be; j += BNODES) {
        int p = pairBuf[j];
        int pos = atomicAdd(&cnt[p >> 17], 1);
        srcSorted[pos] = p & 0x1FFFF;     // writes confined to bucket's ~65KB region
    }
}

// GEMM1: g1[i][f] = dinv[i] * sum_k x[i][k]*W1[k][f].
__global__ void k_gemm1(const float* __restrict__ x, const float* __restrict__ W1,
                        const float* __restrict__ dinv, float* __restrict__ g1, int n) {
    __shared__ float sW[F_IN * F_HID];
    __shared__ float sx[8][F_IN];
    int t = threadIdx.x;
    for (int i = t; i < F_IN * F_HID; i += 256) sW[i] = W1[i];
    int row0 = blockIdx.x * 8;
    for (int i = t; i < 8 * F_IN; i += 256) {
        int r = i >> 7, c = i & 127;
        int gr = row0 + r;
        sx[r][c] = (gr < n) ? x[(long long)gr * F_IN + c] : 0.0f;
    }
    __syncthreads();
    int r = t >> 5;
    int f = t & 31;
    int gr = row0 + r;
    if (gr < n) {
        float acc = 0.0f;
        #pragma unroll
        for (int k = 0; k < F_IN; ++k) acc += sx[r][k] * sW[k * F_HID + f];
        g1[gr * F_HID + f] = acc * dinv[gr];
    }
}

// Gather conv1 + ReLU + tiny GEMM2 fused.
// 8 lanes/node (lane c owns features 4c..4c+3 as float4), 32 nodes/block.
// 4-edge unroll with 4 independent accumulators -> 32 gathers in flight/wave.
__global__ void k_gather1l2(const float4* __restrict__ g1v, const int* __restrict__ srcSorted,
                            const int* __restrict__ cursor, const int* __restrict__ degi,
                            const float* __restrict__ dinv, const float* __restrict__ b1,
                            const float* __restrict__ W2, float* __restrict__ g2p, int n) {
    int t = threadIdx.x;
    int c = t & 7;
    int node = blockIdx.x * 32 + (t >> 3);
    if (node >= n) return;
    int start = cursor[node];
    int end = start + degi[node];
    float4 a0 = g1v[node * 8 + c];   // self-loop init
    float4 a1 = make_float4(0.f, 0.f, 0.f, 0.f), a2 = a1, a3 = a1;
    int j = start;
    for (; j + 4 <= end; j += 4) {
        int s0 = srcSorted[j];
        int s1 = srcSorted[j + 1];
        int s2 = srcSorted[j + 2];
        int s3 = srcSorted[j + 3];
        float4 v0 = g1v[s0 * 8 + c];
        float4 v1 = g1v[s1 * 8 + c];
        float4 v2 = g1v[s2 * 8 + c];
        float4 v3 = g1v[s3 * 8 + c];
        a0 = f4add(a0, v0);
        a1 = f4add(a1, v1);
        a2 = f4add(a2, v2);
        a3 = f4add(a3, v3);
    }
    for (; j < end; ++j) a0 = f4add(a0, g1v[srcSorted[j] * 8 + c]);
    float4 acc = f4add(f4add(a0, a1), f4add(a2, a3));
    float di = dinv[node];
    float4 b4 = ((const float4*)b1)[c];
    float4 h;
    h.x = fmaxf(di * acc.x + b4.x, 0.f);
    h.y = fmaxf(di * acc.y + b4.y, 0.f);
    h.z = fmaxf(di * acc.z + b4.z, 0.f);
    h.w = fmaxf(di * acc.w + b4.w, 0.f);
    float p[F_OUT];
    #pragma unroll
    for (int k = 0; k < F_OUT; ++k) {
        p[k] = h.x * W2[(4 * c + 0) * F_OUT + k]
             + h.y * W2[(4 * c + 1) * F_OUT + k]
             + h.z * W2[(4 * c + 2) * F_OUT + k]
             + h.w * W2[(4 * c + 3) * F_OUT + k];
    }
    #pragma unroll
    for (int m = 1; m < 8; m <<= 1) {
        #pragma unroll
        for (int k = 0; k < F_OUT; ++k) p[k] += __shfl_xor(p[k], m, 64);
    }
    if (c == 0) {
        float4 q0 = make_float4(di * p[0], di * p[1], di * p[2], di * p[3]);
        float4 q1 = make_float4(di * p[4], di * p[5], di * p[6], 0.0f);
        *(float4*)&g2p[node * 8]     = q0;
        *(float4*)&g2p[node * 8 + 4] = q1;
    }
}

// Gather conv2 + bias + log-softmax fused. 8 lanes/node, 4-edge unroll.
__global__ void k_gather2final(const float* __restrict__ g2p, const int* __restrict__ srcSorted,
                               const int* __restrict__ cursor, const int* __restrict__ degi,
                               const float* __restrict__ dinv, const float* __restrict__ b2,
                               float* __restrict__ out, int n) {
    int t = threadIdx.x;
    int c = t & 7;
    int node = blockIdx.x * 32 + (t >> 3);
    if (node >= n) return;
    int start = cursor[node];
    int end = start + degi[node];
    float a0 = g2p[node * 8 + c];     // self-loop init (pad col = 0)
    float a1 = 0.f, a2 = 0.f, a3 = 0.f;
    int j = start;
    for (; j + 4 <= end; j += 4) {
        int s0 = srcSorted[j];
        int s1 = srcSorted[j + 1];
        int s2 = srcSorted[j + 2];
        int s3 = srcSorted[j + 3];
        a0 += g2p[s0 * 8 + c];
        a1 += g2p[s1 * 8 + c];
        a2 += g2p[s2 * 8 + c];
        a3 += g2p[s3 * 8 + c];
    }
    for (; j < end; ++j) a0 += g2p[srcSorted[j] * 8 + c];
    float acc = (a0 + a1) + (a2 + a3);
    float v = dinv[node] * acc + ((c < F_OUT) ? b2[c] : -1e30f);
    float m = v;
    #pragma unroll
    for (int msk = 1; msk < 8; msk <<= 1) m = fmaxf(m, __shfl_xor(m, msk, 64));
    float ex = __expf(v - m);
    float ssum = ex;
    #pragma unroll
    for (int msk = 1; msk < 8; msk <<= 1) ssum += __shfl_xor(ssum, msk, 64);
    float ls = __logf(ssum) + m;
    if (c < F_OUT) out[node * F_OUT + c] = v - ls;
}

extern "C" void kernel_launch(void* const* d_in, const int* in_sizes, int n_in,
                              void* d_out, int out_size, void* d_ws, size_t ws_size,
                              hipStream_t stream) {
    const float* x  = (const float*)d_in[0];
    const int*   ei = (const int*)d_in[1];
    const float* W1 = (const float*)d_in[2];
    const float* b1 = (const float*)d_in[3];
    const float* W2 = (const float*)d_in[4];
    const float* b2 = (const float*)d_in[5];
    float* out = (float*)d_out;

    int n = in_sizes[0] / F_IN;            // 100000
    int E = in_sizes[1] / 2;               // 3200000
    const int* src = ei;
    const int* dst = ei + E;
    int NB = (n + BNODES - 1) >> BSH;      // 196 buckets
    int NT = (E + TILE - 1) / TILE;        // 782 tiles
    int NSCAN = NB * NT;                   // 153272
    int nsb = (NSCAN + 1023) / 1024;       // 150 scan blocks

    // workspace layout (g1 aliases pairBuf: pairBuf dead after k_bucketCSR)
    int*   degi       = (int*)d_ws;                  // [n]
    int*   cursor     = degi + n;                    // [n]
    float* dinv       = (float*)(cursor + n);        // [n]
    int*   srcSorted  = (int*)(dinv + n);            // [E]
    int*   pairBuf    = srcSorted + E;               // [E]  (reused as g1)
    float* g1         = (float*)pairBuf;             // [n*32] == E floats
    float* g2p        = (float*)(pairBuf + E);       // [n*8]
    int*   counts     = (int*)(g2p + (size_t)n * 8); // [NSCAN] tile-major
    int*   tileOffset = counts + NSCAN;              // [NSCAN] bucket-major
    int*   bsum       = tileOffset + NSCAN;          // [nsb]

    k_tileHist<<<NT, 256, 0, stream>>>(dst, E, NB, counts);
    k_scanA<<<nsb, 1024, 0, stream>>>(counts, NSCAN, NB, NT, bsum);
    k_scanB<<<1, 1024, 0, stream>>>(bsum, nsb);
    k_scanC<<<nsb, 1024, 0, stream>>>(counts, NSCAN, NB, NT, bsum, tileOffset);
    k_tileFill<<<NT, 256, 0, stream>>>(src, dst, E, NB, NT, tileOffset, pairBuf);
    k_bucketCSR<<<NB, BNODES, 0, stream>>>(pairBuf, tileOffset, NT, NB, E, n,
                                           degi, cursor, dinv, srcSorted);
    k_gemm1<<<(n + 7) / 8, 256, 0, stream>>>(x, W1, dinv, g1, n);
    k_gather1l2<<<(n + 31) / 32, 256, 0, stream>>>((const float4*)g1, srcSorted, cursor, degi,
                                                   dinv, b1, W2, g2p, n);
    k_gather2final<<<(n + 31) / 32, 256, 0, stream>>>(g2p, srcSorted, cursor, degi, dinv, b2, out, n);
}

// Round 6
// 198.080 us; speedup vs baseline: 4.1970x; 1.0393x over previous
//
#include <hip/hip_runtime.h>
#include <math.h>

// ---------------------------------------------------------------------------
// 2-layer GCN (PyG GCNConv) on MI355X — tiled-partition CSR + MLP-deep gather
// + register-tiled GEMM1 (4x4 per thread, XOR-swizzled LDS, b128 reads).
// out[i] = logsoftmax( dinv[i]*(g2[i] + sum_{e:dst=i} g2[src_e]) + b2 )
// g2 = dinv*( relu( dinv*(g1[i]+sum g1[src]) + b1 ) @ W2 ), g1 = (x@W1)*dinv
// ---------------------------------------------------------------------------

#define F_IN   128
#define F_HID  32
#define F_OUT  7
#define TILE   4096
#define BSH    9              // 512 nodes per bucket
#define BNODES 512
#define GROWS  128            // gemm1 rows per block

__device__ __forceinline__ float4 f4add(float4 a, float4 b) {
    return make_float4(a.x + b.x, a.y + b.y, a.z + b.z, a.w + b.w);
}

// Pass A: per-tile histogram over NB buckets. counts is tile-major [NT][NB].
__global__ void k_tileHist(const int* __restrict__ dst, int E, int NB,
                           int* __restrict__ counts) {
    __shared__ int h[BNODES];
    int tile = blockIdx.x, t = threadIdx.x;
    for (int i = t; i < NB; i += 256) h[i] = 0;
    __syncthreads();
    int base = tile * TILE;
    int lim = base + TILE; if (lim > E) lim = E;
    for (int i = base + t; i < lim; i += 256) atomicAdd(&h[dst[i] >> BSH], 1);
    __syncthreads();
    for (int i = t; i < NB; i += 256) counts[tile * NB + i] = h[i];
}

// Exclusive scan of counts in BUCKET-MAJOR order (idx = b*NT + t).
__global__ void k_scanA(const int* __restrict__ counts, int NSCAN, int NB, int NT,
                        int* __restrict__ bsum) {
    __shared__ int s[1024];
    int t = threadIdx.x;
    int idx = blockIdx.x * 1024 + t;
    int v = 0;
    if (idx < NSCAN) { int b = idx / NT, tt = idx - b * NT; v = counts[tt * NB + b]; }
    s[t] = v;
    __syncthreads();
    for (int off = 512; off > 0; off >>= 1) {
        if (t < off) s[t] += s[t + off];
        __syncthreads();
    }
    if (t == 0) bsum[blockIdx.x] = s[0];
}

__global__ void k_scanB(int* __restrict__ bsum, int nb) {  // nb <= 1024
    __shared__ int s[1024];
    int t = threadIdx.x;
    int v = (t < nb) ? bsum[t] : 0;
    s[t] = v;
    __syncthreads();
    for (int off = 1; off < 1024; off <<= 1) {
        int a = (t >= off) ? s[t - off] : 0;
        __syncthreads();
        s[t] += a;
        __syncthreads();
    }
    if (t < nb) bsum[t] = s[t] - v;
}

__global__ void k_scanC(const int* __restrict__ counts, int NSCAN, int NB, int NT,
                        const int* __restrict__ bsum, int* __restrict__ tileOffset) {
    __shared__ int s[1024];
    int t = threadIdx.x;
    int idx = blockIdx.x * 1024 + t;
    int v = 0;
    if (idx < NSCAN) { int b = idx / NT, tt = idx - b * NT; v = counts[tt * NB + b]; }
    s[t] = v;
    __syncthreads();
    for (int off = 1; off < 1024; off <<= 1) {
        int a = (t >= off) ? s[t - off] : 0;
        __syncthreads();
        s[t] += a;
        __syncthreads();
    }
    if (idx < NSCAN) tileOffset[idx] = bsum[blockIdx.x] + s[t] - v;  // bucket-major linear
}

// Pass B: scatter packed (local9|src17) into per-(tile,bucket) contiguous runs.
__global__ void k_tileFill(const int* __restrict__ src, const int* __restrict__ dst,
                           int E, int NB, int NT, const int* __restrict__ tileOffset,
                           int* __restrict__ pairBuf) {
    __shared__ int lcur[BNODES];
    int tile = blockIdx.x, t = threadIdx.x;
    for (int i = t; i < NB; i += 256) lcur[i] = tileOffset[i * NT + tile];
    __syncthreads();
    int base = tile * TILE;
    int lim = base + TILE; if (lim > E) lim = E;
    for (int i = base + t; i < lim; i += 256) {
        int s = src[i], d = dst[i];
        int b = d >> BSH;
        int pos = atomicAdd(&lcur[b], 1);              // LDS cursor, run is tile-private
        pairBuf[pos] = ((d & (BNODES - 1)) << 17) | s; // src < 2^17
    }
}

// Pass C: per-bucket CSR finish — degi/cursor/dinv + srcSorted placement.
__global__ void k_bucketCSR(const int* __restrict__ pairBuf, const int* __restrict__ tileOffset,
                            int NT, int NB, int E, int n,
                            int* __restrict__ degi, int* __restrict__ cursor,
                            float* __restrict__ dinv, int* __restrict__ srcSorted) {
    __shared__ int cnt[BNODES];
    __shared__ int pref[BNODES];
    int b = blockIdx.x, t = threadIdx.x;
    cnt[t] = 0;
    __syncthreads();
    int bs = tileOffset[b * NT];
    int be = (b + 1 < NB) ? tileOffset[(b + 1) * NT] : E;
    for (int j = bs + t; j < be; j += BNODES) atomicAdd(&cnt[pairBuf[j] >> 17], 1);
    __syncthreads();
    int v = cnt[t];
    pref[t] = v;
    __syncthreads();
    for (int off = 1; off < BNODES; off <<= 1) {
        int a = (t >= off) ? pref[t - off] : 0;
        __syncthreads();
        pref[t] += a;
        __syncthreads();
    }
    int ex = pref[t] - v;                 // exclusive prefix within bucket
    int node = (b << BSH) + t;
    if (node < n) {
        degi[node]   = v;
        cursor[node] = bs + ex;
        dinv[node]   = rsqrtf((float)v + 1.0f);  // +1 self-loop
    }
    __syncthreads();
    cnt[t] = bs + ex;                     // reuse as placement cursors
    __syncthreads();
    for (int j = bs + t; j < be; j += BNODES) {
        int p = pairBuf[j];
        int pos = atomicAdd(&cnt[p >> 17], 1);
        srcSorted[pos] = p & 0x1FFFF;     // writes confined to bucket's ~65KB region
    }
}

// Transpose W1 [128][32] -> W1t [32][128] (one block; tiny).
__global__ void k_wT(const float* __restrict__ W1, float* __restrict__ W1t) {
    int t = threadIdx.x;
    for (int i = 0; i < 16; ++i) {
        int idx = t + i * 256;            // 4096 elements
        int k = idx >> 5, c = idx & 31;
        W1t[c * F_IN + k] = W1[idx];
    }
}

// GEMM1, register-tiled: block = 128 rows x 32 cols, thread = 4x4 outputs.
// sx[128][128] and sw[32][128] in LDS, XOR-swizzled on (k>>2) bank-group bits
// so all ds_read_b128 are conflict-free. 8 b128 reads per 64 FMAs (2 B/FMA).
__global__ void k_gemm1(const float* __restrict__ x, const float* __restrict__ W1t,
                        const float* __restrict__ dinv, float* __restrict__ g1, int n) {
    __shared__ float sx[GROWS * F_IN];    // 64 KB
    __shared__ float sw[F_HID * F_IN];    // 16 KB
    int t = threadIdx.x;
    int row0 = blockIdx.x * GROWS;
    // stage W1t (1024 float4s), swizzle slot = (kq&24) | ((kq&7) ^ ((c>>2)&7))
    #pragma unroll
    for (int i = 0; i < 4; ++i) {
        int f4 = t + i * 256;
        int c = f4 >> 5, kq = f4 & 31;
        int slot = (kq & 24) | ((kq & 7) ^ ((c >> 2) & 7));
        ((float4*)sw)[c * 32 + slot] = ((const float4*)W1t)[f4];
    }
    // stage x tile (4096 float4s), same swizzle keyed on (r>>2)&7
    #pragma unroll
    for (int i = 0; i < 16; ++i) {
        int f4 = t + i * 256;
        int r = f4 >> 5, kq = f4 & 31;
        int gr = row0 + r;
        float4 v = (gr < n) ? ((const float4*)x)[(size_t)gr * 32 + kq]
                            : make_float4(0.f, 0.f, 0.f, 0.f);
        int slot = (kq & 24) | ((kq & 7) ^ ((r >> 2) & 7));
        ((float4*)sx)[r * 32 + slot] = v;
    }
    __syncthreads();
    int rt = t >> 3;   // 0..31 -> rows 4rt..4rt+3
    int ct = t & 7;    // 0..7  -> cols 4ct..4ct+3
    float acc[4][4];
    #pragma unroll
    for (int i = 0; i < 4; ++i)
        #pragma unroll
        for (int j = 0; j < 4; ++j) acc[i][j] = 0.f;
    for (int kq = 0; kq < 32; ++kq) {
        int xslot = (kq & 24) | ((kq & 7) ^ (rt & 7));
        int wslot = (kq & 24) | ((kq & 7) ^ (ct & 7));
        float4 xv[4], wv[4];
        #pragma unroll
        for (int i = 0; i < 4; ++i) xv[i] = ((float4*)sx)[(4 * rt + i) * 32 + xslot];
        #pragma unroll
        for (int j = 0; j < 4; ++j) wv[j] = ((float4*)sw)[(4 * ct + j) * 32 + wslot];
        #pragma unroll
        for (int i = 0; i < 4; ++i)
            #pragma unroll
            for (int j = 0; j < 4; ++j)
                acc[i][j] += xv[i].x * wv[j].x + xv[i].y * wv[j].y
                           + xv[i].z * wv[j].z + xv[i].w * wv[j].w;
    }
    #pragma unroll
    for (int i = 0; i < 4; ++i) {
        int row = row0 + 4 * rt + i;
        if (row < n) {
            float di = dinv[row];
            ((float4*)g1)[(size_t)row * 8 + ct] =
                make_float4(acc[i][0] * di, acc[i][1] * di, acc[i][2] * di, acc[i][3] * di);
        }
    }
}

// Gather conv1 + ReLU + tiny GEMM2 fused.
// 8 lanes/node (lane c owns features 4c..4c+3 as float4), 32 nodes/block.
// 4-edge unroll with 4 independent accumulators -> 32 gathers in flight/wave.
__global__ void k_gather1l2(const float4* __restrict__ g1v, const int* __restrict__ srcSorted,
                            const int* __restrict__ cursor, const int* __restrict__ degi,
                            const float* __restrict__ dinv, const float* __restrict__ b1,
                            const float* __restrict__ W2, float* __restrict__ g2p, int n) {
    int t = threadIdx.x;
    int c = t & 7;
    int node = blockIdx.x * 32 + (t >> 3);
    if (node >= n) return;
    int start = cursor[node];
    int end = start + degi[node];
    float4 a0 = g1v[node * 8 + c];   // self-loop init
    float4 a1 = make_float4(0.f, 0.f, 0.f, 0.f), a2 = a1, a3 = a1;
    int j = start;
    for (; j + 4 <= end; j += 4) {
        int s0 = srcSorted[j];
        int s1 = srcSorted[j + 1];
        int s2 = srcSorted[j + 2];
        int s3 = srcSorted[j + 3];
        float4 v0 = g1v[s0 * 8 + c];
        float4 v1 = g1v[s1 * 8 + c];
        float4 v2 = g1v[s2 * 8 + c];
        float4 v3 = g1v[s3 * 8 + c];
        a0 = f4add(a0, v0);
        a1 = f4add(a1, v1);
        a2 = f4add(a2, v2);
        a3 = f4add(a3, v3);
    }
    for (; j < end; ++j) a0 = f4add(a0, g1v[srcSorted[j] * 8 + c]);
    float4 acc = f4add(f4add(a0, a1), f4add(a2, a3));
    float di = dinv[node];
    float4 b4 = ((const float4*)b1)[c];
    float4 h;
    h.x = fmaxf(di * acc.x + b4.x, 0.f);
    h.y = fmaxf(di * acc.y + b4.y, 0.f);
    h.z = fmaxf(di * acc.z + b4.z, 0.f);
    h.w = fmaxf(di * acc.w + b4.w, 0.f);
    float p[F_OUT];
    #pragma unroll
    for (int k = 0; k < F_OUT; ++k) {
        p[k] = h.x * W2[(4 * c + 0) * F_OUT + k]
             + h.y * W2[(4 * c + 1) * F_OUT + k]
             + h.z * W2[(4 * c + 2) * F_OUT + k]
             + h.w * W2[(4 * c + 3) * F_OUT + k];
    }
    #pragma unroll
    for (int m = 1; m < 8; m <<= 1) {
        #pragma unroll
        for (int k = 0; k < F_OUT; ++k) p[k] += __shfl_xor(p[k], m, 64);
    }
    if (c == 0) {
        float4 q0 = make_float4(di * p[0], di * p[1], di * p[2], di * p[3]);
        float4 q1 = make_float4(di * p[4], di * p[5], di * p[6], 0.0f);
        *(float4*)&g2p[node * 8]     = q0;
        *(float4*)&g2p[node * 8 + 4] = q1;
    }
}

// Gather conv2 + bias + log-softmax fused. 8 lanes/node, 4-edge unroll.
__global__ void k_gather2final(const float* __restrict__ g2p, const int* __restrict__ srcSorted,
                               const int* __restrict__ cursor, const int* __restrict__ degi,
                               const float* __restrict__ dinv, const float* __restrict__ b2,
                               float* __restrict__ out, int n) {
    int t = threadIdx.x;
    int c = t & 7;
    int node = blockIdx.x * 32 + (t >> 3);
    if (node >= n) return;
    int start = cursor[node];
    int end = start + degi[node];
    float a0 = g2p[node * 8 + c];     // self-loop init (pad col = 0)
    float a1 = 0.f, a2 = 0.f, a3 = 0.f;
    int j = start;
    for (; j + 4 <= end; j += 4) {
        int s0 = srcSorted[j];
        int s1 = srcSorted[j + 1];
        int s2 = srcSorted[j + 2];
        int s3 = srcSorted[j + 3];
        a0 += g2p[s0 * 8 + c];
        a1 += g2p[s1 * 8 + c];
        a2 += g2p[s2 * 8 + c];
        a3 += g2p[s3 * 8 + c];
    }
    for (; j < end; ++j) a0 += g2p[srcSorted[j] * 8 + c];
    float acc = (a0 + a1) + (a2 + a3);
    float v = dinv[node] * acc + ((c < F_OUT) ? b2[c] : -1e30f);
    float m = v;
    #pragma unroll
    for (int msk = 1; msk < 8; msk <<= 1) m = fmaxf(m, __shfl_xor(m, msk, 64));
    float ex = __expf(v - m);
    float ssum = ex;
    #pragma unroll
    for (int msk = 1; msk < 8; msk <<= 1) ssum += __shfl_xor(ssum, msk, 64);
    float ls = __logf(ssum) + m;
    if (c < F_OUT) out[node * F_OUT + c] = v - ls;
}

extern "C" void kernel_launch(void* const* d_in, const int* in_sizes, int n_in,
                              void* d_out, int out_size, void* d_ws, size_t ws_size,
                              hipStream_t stream) {
    const float* x  = (const float*)d_in[0];
    const int*   ei = (const int*)d_in[1];
    const float* W1 = (const float*)d_in[2];
    const float* b1 = (const float*)d_in[3];
    const float* W2 = (const float*)d_in[4];
    const float* b2 = (const float*)d_in[5];
    float* out = (float*)d_out;

    int n = in_sizes[0] / F_IN;            // 100000
    int E = in_sizes[1] / 2;               // 3200000
    const int* src = ei;
    const int* dst = ei + E;
    int NB = (n + BNODES - 1) >> BSH;      // 196 buckets
    int NT = (E + TILE - 1) / TILE;        // 782 tiles
    int NSCAN = NB * NT;                   // 153272
    int nsb = (NSCAN + 1023) / 1024;       // 150 scan blocks

    // workspace layout (g1 aliases pairBuf: pairBuf dead after k_bucketCSR)
    int*   degi       = (int*)d_ws;                  // [n]
    int*   cursor     = degi + n;                    // [n]
    float* dinv       = (float*)(cursor + n);        // [n]
    int*   srcSorted  = (int*)(dinv + n);            // [E]
    int*   pairBuf    = srcSorted + E;               // [E]  (reused as g1)
    float* g1         = (float*)pairBuf;             // [n*32] == E floats
    float* g2p        = (float*)(pairBuf + E);       // [n*8]
    int*   counts     = (int*)(g2p + (size_t)n * 8); // [NSCAN] tile-major
    int*   tileOffset = counts + NSCAN;              // [NSCAN] bucket-major
    int*   bsum       = tileOffset + NSCAN;          // [nsb]
    float* W1t        = (float*)(bsum + nsb);        // [4096]

    k_wT<<<1, 256, 0, stream>>>(W1, W1t);
    k_tileHist<<<NT, 256, 0, stream>>>(dst, E, NB, counts);
    k_scanA<<<nsb, 1024, 0, stream>>>(counts, NSCAN, NB, NT, bsum);
    k_scanB<<<1, 1024, 0, stream>>>(bsum, nsb);
    k_scanC<<<nsb, 1024, 0, stream>>>(counts, NSCAN, NB, NT, bsum, tileOffset);
    k_tileFill<<<NT, 256, 0, stream>>>(src, dst, E, NB, NT, tileOffset, pairBuf);
    k_bucketCSR<<<NB, BNODES, 0, stream>>>(pairBuf, tileOffset, NT, NB, E, n,
                                           degi, cursor, dinv, srcSorted);
    k_gemm1<<<(n + GROWS - 1) / GROWS, 256, 0, stream>>>(x, W1t, dinv, g1, n);
    k_gather1l2<<<(n + 31) / 32, 256, 0, stream>>>((const float4*)g1, srcSorted, cursor, degi,
                                                   dinv, b1, W2, g2p, n);
    k_gather2final<<<(n + 31) / 32, 256, 0, stream>>>(g2p, srcSorted, cursor, degi, dinv, b2, out, n);
}

// Round 7
// 179.243 us; speedup vs baseline: 4.6380x; 1.1051x over previous
//
#include <hip/hip_runtime.h>
#include <math.h>

// ---------------------------------------------------------------------------
// 2-layer GCN (PyG GCNConv) on MI355X — tiled-partition CSR + MLP-deep gather
// + register-tiled GEMM1. Gathered activations (g1, g2) stored as bf16 to
// halve gather traffic and shrink the random-access working set
// (g1: 12.8->6.4 MB, g2: 3.2->1.6 MB ~ L2-resident). All accumulation fp32.
// ---------------------------------------------------------------------------

#define F_IN   128
#define F_HID  32
#define F_OUT  7
#define TILE   4096
#define BSH    9              // 512 nodes per bucket
#define BNODES 512
#define GROWS  128            // gemm1 rows per block

__device__ __forceinline__ float bf2f(unsigned short u) {
    return __uint_as_float(((unsigned int)u) << 16);
}
__device__ __forceinline__ unsigned short f2bf(float f) {
    unsigned int u = __float_as_uint(f);
    u += 0x7FFF + ((u >> 16) & 1);   // round-to-nearest-even
    return (unsigned short)(u >> 16);
}
__device__ __forceinline__ unsigned int pack2(unsigned short lo, unsigned short hi) {
    return (unsigned int)lo | ((unsigned int)hi << 16);
}

// Pass A: per-tile histogram over NB buckets. counts is tile-major [NT][NB].
__global__ void k_tileHist(const int* __restrict__ dst, int E, int NB,
                           int* __restrict__ counts) {
    __shared__ int h[BNODES];
    int tile = blockIdx.x, t = threadIdx.x;
    for (int i = t; i < NB; i += 256) h[i] = 0;
    __syncthreads();
    int base = tile * TILE;
    int lim = base + TILE; if (lim > E) lim = E;
    for (int i = base + t; i < lim; i += 256) atomicAdd(&h[dst[i] >> BSH], 1);
    __syncthreads();
    for (int i = t; i < NB; i += 256) counts[tile * NB + i] = h[i];
}

// Exclusive scan of counts in BUCKET-MAJOR order (idx = b*NT + t).
__global__ void k_scanA(const int* __restrict__ counts, int NSCAN, int NB, int NT,
                        int* __restrict__ bsum) {
    __shared__ int s[1024];
    int t = threadIdx.x;
    int idx = blockIdx.x * 1024 + t;
    int v = 0;
    if (idx < NSCAN) { int b = idx / NT, tt = idx - b * NT; v = counts[tt * NB + b]; }
    s[t] = v;
    __syncthreads();
    for (int off = 512; off > 0; off >>= 1) {
        if (t < off) s[t] += s[t + off];
        __syncthreads();
    }
    if (t == 0) bsum[blockIdx.x] = s[0];
}

__global__ void k_scanB(int* __restrict__ bsum, int nb) {  // nb <= 1024
    __shared__ int s[1024];
    int t = threadIdx.x;
    int v = (t < nb) ? bsum[t] : 0;
    s[t] = v;
    __syncthreads();
    for (int off = 1; off < 1024; off <<= 1) {
        int a = (t >= off) ? s[t - off] : 0;
        __syncthreads();
        s[t] += a;
        __syncthreads();
    }
    if (t < nb) bsum[t] = s[t] - v;
}

__global__ void k_scanC(const int* __restrict__ counts, int NSCAN, int NB, int NT,
                        const int* __restrict__ bsum, int* __restrict__ tileOffset) {
    __shared__ int s[1024];
    int t = threadIdx.x;
    int idx = blockIdx.x * 1024 + t;
    int v = 0;
    if (idx < NSCAN) { int b = idx / NT, tt = idx - b * NT; v = counts[tt * NB + b]; }
    s[t] = v;
    __syncthreads();
    for (int off = 1; off < 1024; off <<= 1) {
        int a = (t >= off) ? s[t - off] : 0;
        __syncthreads();
        s[t] += a;
        __syncthreads();
    }
    if (idx < NSCAN) tileOffset[idx] = bsum[blockIdx.x] + s[t] - v;  // bucket-major linear
}

// Pass B: scatter packed (local9|src17) into per-(tile,bucket) contiguous runs.
__global__ void k_tileFill(const int* __restrict__ src, const int* __restrict__ dst,
                           int E, int NB, int NT, const int* __restrict__ tileOffset,
                           int* __restrict__ pairBuf) {
    __shared__ int lcur[BNODES];
    int tile = blockIdx.x, t = threadIdx.x;
    for (int i = t; i < NB; i += 256) lcur[i] = tileOffset[i * NT + tile];
    __syncthreads();
    int base = tile * TILE;
    int lim = base + TILE; if (lim > E) lim = E;
    for (int i = base + t; i < lim; i += 256) {
        int s = src[i], d = dst[i];
        int b = d >> BSH;
        int pos = atomicAdd(&lcur[b], 1);              // LDS cursor, run is tile-private
        pairBuf[pos] = ((d & (BNODES - 1)) << 17) | s; // src < 2^17
    }
}

// Pass C: per-bucket CSR finish — degi/cursor/dinv + srcSorted placement.
__global__ void k_bucketCSR(const int* __restrict__ pairBuf, const int* __restrict__ tileOffset,
                            int NT, int NB, int E, int n,
                            int* __restrict__ degi, int* __restrict__ cursor,
                            float* __restrict__ dinv, int* __restrict__ srcSorted) {
    __shared__ int cnt[BNODES];
    __shared__ int pref[BNODES];
    int b = blockIdx.x, t = threadIdx.x;
    cnt[t] = 0;
    __syncthreads();
    int bs = tileOffset[b * NT];
    int be = (b + 1 < NB) ? tileOffset[(b + 1) * NT] : E;
    for (int j = bs + t; j < be; j += BNODES) atomicAdd(&cnt[pairBuf[j] >> 17], 1);
    __syncthreads();
    int v = cnt[t];
    pref[t] = v;
    __syncthreads();
    for (int off = 1; off < BNODES; off <<= 1) {
        int a = (t >= off) ? pref[t - off] : 0;
        __syncthreads();
        pref[t] += a;
        __syncthreads();
    }
    int ex = pref[t] - v;                 // exclusive prefix within bucket
    int node = (b << BSH) + t;
    if (node < n) {
        degi[node]   = v;
        cursor[node] = bs + ex;
        dinv[node]   = rsqrtf((float)v + 1.0f);  // +1 self-loop
    }
    __syncthreads();
    cnt[t] = bs + ex;                     // reuse as placement cursors
    __syncthreads();
    for (int j = bs + t; j < be; j += BNODES) {
        int p = pairBuf[j];
        int pos = atomicAdd(&cnt[p >> 17], 1);
        srcSorted[pos] = p & 0x1FFFF;     // writes confined to bucket's ~65KB region
    }
}

// Transpose W1 [128][32] -> W1t [32][128] (one block; tiny).
__global__ void k_wT(const float* __restrict__ W1, float* __restrict__ W1t) {
    int t = threadIdx.x;
    for (int i = 0; i < 16; ++i) {
        int idx = t + i * 256;            // 4096 elements
        int k = idx >> 5, c = idx & 31;
        W1t[c * F_IN + k] = W1[idx];
    }
}

// GEMM1, register-tiled: block = 128 rows x 32 cols, thread = 4x4 outputs.
// sx[128][128] and sw[32][128] in LDS, XOR-swizzled on (k>>2) bank-group bits
// so all ds_read_b128 are conflict-free. Epilogue packs bf16 rows.
__global__ void k_gemm1(const float* __restrict__ x, const float* __restrict__ W1t,
                        const float* __restrict__ dinv, unsigned short* __restrict__ g1b,
                        int n) {
    __shared__ float sx[GROWS * F_IN];    // 64 KB
    __shared__ float sw[F_HID * F_IN];    // 16 KB
    int t = threadIdx.x;
    int row0 = blockIdx.x * GROWS;
    #pragma unroll
    for (int i = 0; i < 4; ++i) {
        int f4 = t + i * 256;
        int c = f4 >> 5, kq = f4 & 31;
        int slot = (kq & 24) | ((kq & 7) ^ ((c >> 2) & 7));
        ((float4*)sw)[c * 32 + slot] = ((const float4*)W1t)[f4];
    }
    #pragma unroll
    for (int i = 0; i < 16; ++i) {
        int f4 = t + i * 256;
        int r = f4 >> 5, kq = f4 & 31;
        int gr = row0 + r;
        float4 v = (gr < n) ? ((const float4*)x)[(size_t)gr * 32 + kq]
                            : make_float4(0.f, 0.f, 0.f, 0.f);
        int slot = (kq & 24) | ((kq & 7) ^ ((r >> 2) & 7));
        ((float4*)sx)[r * 32 + slot] = v;
    }
    __syncthreads();
    int rt = t >> 3;   // 0..31 -> rows 4rt..4rt+3
    int ct = t & 7;    // 0..7  -> cols 4ct..4ct+3
    float acc[4][4];
    #pragma unroll
    for (int i = 0; i < 4; ++i)
        #pragma unroll
        for (int j = 0; j < 4; ++j) acc[i][j] = 0.f;
    for (int kq = 0; kq < 32; ++kq) {
        int xslot = (kq & 24) | ((kq & 7) ^ (rt & 7));
        int wslot = (kq & 24) | ((kq & 7) ^ (ct & 7));
        float4 xv[4], wv[4];
        #pragma unroll
        for (int i = 0; i < 4; ++i) xv[i] = ((float4*)sx)[(4 * rt + i) * 32 + xslot];
        #pragma unroll
        for (int j = 0; j < 4; ++j) wv[j] = ((float4*)sw)[(4 * ct + j) * 32 + wslot];
        #pragma unroll
        for (int i = 0; i < 4; ++i)
            #pragma unroll
            for (int j = 0; j < 4; ++j)
                acc[i][j] += xv[i].x * wv[j].x + xv[i].y * wv[j].y
                           + xv[i].z * wv[j].z + xv[i].w * wv[j].w;
    }
    #pragma unroll
    for (int i = 0; i < 4; ++i) {
        int row = row0 + 4 * rt + i;
        if (row < n) {
            float di = dinv[row];
            ushort4 o;
            o.x = f2bf(acc[i][0] * di);
            o.y = f2bf(acc[i][1] * di);
            o.z = f2bf(acc[i][2] * di);
            o.w = f2bf(acc[i][3] * di);
            ((ushort4*)g1b)[(size_t)row * 8 + ct] = o;
        }
    }
}

// Gather conv1 + ReLU + tiny GEMM2 fused.
// 8 lanes/node (lane c owns 4 bf16 feats as ushort4), 32 nodes/block.
// 4-edge unroll with 4 independent fp32 accumulators.
__global__ void k_gather1l2(const ushort4* __restrict__ g1v, const int* __restrict__ srcSorted,
                            const int* __restrict__ cursor, const int* __restrict__ degi,
                            const float* __restrict__ dinv, const float* __restrict__ b1,
                            const float* __restrict__ W2, unsigned int* __restrict__ g2b,
                            int n) {
    int t = threadIdx.x;
    int c = t & 7;
    int node = blockIdx.x * 32 + (t >> 3);
    if (node >= n) return;
    int start = cursor[node];
    int end = start + degi[node];
    ushort4 sv = g1v[node * 8 + c];   // self-loop init
    float ax = bf2f(sv.x), ay = bf2f(sv.y), az = bf2f(sv.z), aw = bf2f(sv.w);
    float bx = 0.f, by = 0.f, bz = 0.f, bw = 0.f;
    float cx = 0.f, cy = 0.f, cz = 0.f, cw = 0.f;
    float dx = 0.f, dy = 0.f, dz = 0.f, dw = 0.f;
    int j = start;
    for (; j + 4 <= end; j += 4) {
        int s0 = srcSorted[j];
        int s1 = srcSorted[j + 1];
        int s2 = srcSorted[j + 2];
        int s3 = srcSorted[j + 3];
        ushort4 v0 = g1v[s0 * 8 + c];
        ushort4 v1 = g1v[s1 * 8 + c];
        ushort4 v2 = g1v[s2 * 8 + c];
        ushort4 v3 = g1v[s3 * 8 + c];
        ax += bf2f(v0.x); ay += bf2f(v0.y); az += bf2f(v0.z); aw += bf2f(v0.w);
        bx += bf2f(v1.x); by += bf2f(v1.y); bz += bf2f(v1.z); bw += bf2f(v1.w);
        cx += bf2f(v2.x); cy += bf2f(v2.y); cz += bf2f(v2.z); cw += bf2f(v2.w);
        dx += bf2f(v3.x); dy += bf2f(v3.y); dz += bf2f(v3.z); dw += bf2f(v3.w);
    }
    for (; j < end; ++j) {
        ushort4 v0 = g1v[srcSorted[j] * 8 + c];
        ax += bf2f(v0.x); ay += bf2f(v0.y); az += bf2f(v0.z); aw += bf2f(v0.w);
    }
    float accx = (ax + bx) + (cx + dx);
    float accy = (ay + by) + (cy + dy);
    float accz = (az + bz) + (cz + dz);
    float accw = (aw + bw) + (cw + dw);
    float di = dinv[node];
    float4 b4 = ((const float4*)b1)[c];
    float hx = fmaxf(di * accx + b4.x, 0.f);
    float hy = fmaxf(di * accy + b4.y, 0.f);
    float hz = fmaxf(di * accz + b4.z, 0.f);
    float hw = fmaxf(di * accw + b4.w, 0.f);
    float p[F_OUT];
    #pragma unroll
    for (int k = 0; k < F_OUT; ++k) {
        p[k] = hx * W2[(4 * c + 0) * F_OUT + k]
             + hy * W2[(4 * c + 1) * F_OUT + k]
             + hz * W2[(4 * c + 2) * F_OUT + k]
             + hw * W2[(4 * c + 3) * F_OUT + k];
    }
    #pragma unroll
    for (int m = 1; m < 8; m <<= 1) {
        #pragma unroll
        for (int k = 0; k < F_OUT; ++k) p[k] += __shfl_xor(p[k], m, 64);
    }
    if (c == 0) {
        uint4 q;
        q.x = pack2(f2bf(di * p[0]), f2bf(di * p[1]));
        q.y = pack2(f2bf(di * p[2]), f2bf(di * p[3]));
        q.z = pack2(f2bf(di * p[4]), f2bf(di * p[5]));
        q.w = pack2(f2bf(di * p[6]), 0);
        *(uint4*)&g2b[node * 4] = q;      // 16B bf16 row (8 slots, last = 0)
    }
}

// Gather conv2 + bias + log-softmax fused. 8 lanes/node, 4-edge unroll.
// g2 rows are 16B bf16 (L2-resident working set).
__global__ void k_gather2final(const unsigned short* __restrict__ g2b,
                               const int* __restrict__ srcSorted,
                               const int* __restrict__ cursor, const int* __restrict__ degi,
                               const float* __restrict__ dinv, const float* __restrict__ b2,
                               float* __restrict__ out, int n) {
    int t = threadIdx.x;
    int c = t & 7;
    int node = blockIdx.x * 32 + (t >> 3);
    if (node >= n) return;
    int start = cursor[node];
    int end = start + degi[node];
    float a0 = bf2f(g2b[node * 8 + c]);   // self-loop init (pad col = 0)
    float a1 = 0.f, a2 = 0.f, a3 = 0.f;
    int j = start;
    for (; j + 4 <= end; j += 4) {
        int s0 = srcSorted[j];
        int s1 = srcSorted[j + 1];
        int s2 = srcSorted[j + 2];
        int s3 = srcSorted[j + 3];
        a0 += bf2f(g2b[s0 * 8 + c]);
        a1 += bf2f(g2b[s1 * 8 + c]);
        a2 += bf2f(g2b[s2 * 8 + c]);
        a3 += bf2f(g2b[s3 * 8 + c]);
    }
    for (; j < end; ++j) a0 += bf2f(g2b[srcSorted[j] * 8 + c]);
    float acc = (a0 + a1) + (a2 + a3);
    float v = dinv[node] * acc + ((c < F_OUT) ? b2[c] : -1e30f);
    float m = v;
    #pragma unroll
    for (int msk = 1; msk < 8; msk <<= 1) m = fmaxf(m, __shfl_xor(m, msk, 64));
    float ex = __expf(v - m);
    float ssum = ex;
    #pragma unroll
    for (int msk = 1; msk < 8; msk <<= 1) ssum += __shfl_xor(ssum, msk, 64);
    float ls = __logf(ssum) + m;
    if (c < F_OUT) out[node * F_OUT + c] = v - ls;
}

extern "C" void kernel_launch(void* const* d_in, const int* in_sizes, int n_in,
                              void* d_out, int out_size, void* d_ws, size_t ws_size,
                              hipStream_t stream) {
    const float* x  = (const float*)d_in[0];
    const int*   ei = (const int*)d_in[1];
    const float* W1 = (const float*)d_in[2];
    const float* b1 = (const float*)d_in[3];
    const float* W2 = (const float*)d_in[4];
    const float* b2 = (const float*)d_in[5];
    float* out = (float*)d_out;

    int n = in_sizes[0] / F_IN;            // 100000
    int E = in_sizes[1] / 2;               // 3200000
    const int* src = ei;
    const int* dst = ei + E;
    int NB = (n + BNODES - 1) >> BSH;      // 196 buckets
    int NT = (E + TILE - 1) / TILE;        // 782 tiles
    int NSCAN = NB * NT;                   // 153272
    int nsb = (NSCAN + 1023) / 1024;       // 150 scan blocks

    // workspace layout (g1b aliases pairBuf: pairBuf dead after k_bucketCSR)
    int*            degi       = (int*)d_ws;                  // [n]
    int*            cursor     = degi + n;                    // [n]
    float*          dinv       = (float*)(cursor + n);        // [n]
    int*            srcSorted  = (int*)(dinv + n);            // [E]
    int*            pairBuf    = srcSorted + E;               // [E] (reused as g1b)
    unsigned short* g1b        = (unsigned short*)pairBuf;    // [n*32] bf16 (= E/2 ints)
    unsigned short* g2b        = (unsigned short*)(pairBuf + E); // [n*8] bf16
    int*            counts     = (int*)(g2b + (size_t)n * 8); // [NSCAN] tile-major
    int*            tileOffset = counts + NSCAN;              // [NSCAN] bucket-major
    int*            bsum       = tileOffset + NSCAN;          // [nsb]
    float*          W1t        = (float*)(bsum + nsb);        // [4096]

    k_wT<<<1, 256, 0, stream>>>(W1, W1t);
    k_tileHist<<<NT, 256, 0, stream>>>(dst, E, NB, counts);
    k_scanA<<<nsb, 1024, 0, stream>>>(counts, NSCAN, NB, NT, bsum);
    k_scanB<<<1, 1024, 0, stream>>>(bsum, nsb);
    k_scanC<<<nsb, 1024, 0, stream>>>(counts, NSCAN, NB, NT, bsum, tileOffset);
    k_tileFill<<<NT, 256, 0, stream>>>(src, dst, E, NB, NT, tileOffset, pairBuf);
    k_bucketCSR<<<NB, BNODES, 0, stream>>>(pairBuf, tileOffset, NT, NB, E, n,
                                           degi, cursor, dinv, srcSorted);
    k_gemm1<<<(n + GROWS - 1) / GROWS, 256, 0, stream>>>(x, W1t, dinv, g1b, n);
    k_gather1l2<<<(n + 31) / 32, 256, 0, stream>>>((const ushort4*)g1b, srcSorted, cursor, degi,
                                                   dinv, b1, W2, (unsigned int*)g2b, n);
    k_gather2final<<<(n + 31) / 32, 256, 0, stream>>>(g2b, srcSorted, cursor, degi, dinv, b2, out, n);
}

// Round 8
// 158.319 us; speedup vs baseline: 5.2510x; 1.1322x over previous
//
#include <hip/hip_runtime.h>
#include <math.h>

// ---------------------------------------------------------------------------
// 2-layer GCN (PyG GCNConv) on MI355X — tiled-partition CSR + MLP-deep gather.
// GEMM1 via bf16 MFMA (no LDS, direct global A-frags, preconverted W frags).
// tileFill gets a bijective XCD-chunked tile swizzle so adjacent pairBuf runs
// stay in one XCD's L2 (kills run-boundary line ping-pong).
// out[i] = logsoftmax( dinv[i]*(g2[i] + sum_{e:dst=i} g2[src_e]) + b2 )
// g2 = dinv*( relu( dinv*(g1[i]+sum g1[src]) + b1 ) @ W2 ), g1 = (x@W1)*dinv
// ---------------------------------------------------------------------------

#define F_IN   128
#define F_HID  32
#define F_OUT  7
#define TILE   4096
#define BSH    9              // 512 nodes per bucket
#define BNODES 512

typedef __attribute__((ext_vector_type(8))) short bf16x8;
typedef __attribute__((ext_vector_type(4))) float f32x4;

__device__ __forceinline__ float bf2f(unsigned short u) {
    return __uint_as_float(((unsigned int)u) << 16);
}
__device__ __forceinline__ unsigned short f2bf(float f) {
    unsigned int u = __float_as_uint(f);
    u += 0x7FFF + ((u >> 16) & 1);   // round-to-nearest-even
    return (unsigned short)(u >> 16);
}
__device__ __forceinline__ unsigned int pack2(unsigned short lo, unsigned short hi) {
    return (unsigned int)lo | ((unsigned int)hi << 16);
}

// Pass A: per-tile histogram over NB buckets. counts is tile-major [NT][NB].
__global__ void k_tileHist(const int* __restrict__ dst, int E, int NB,
                           int* __restrict__ counts) {
    __shared__ int h[BNODES];
    int tile = blockIdx.x, t = threadIdx.x;
    for (int i = t; i < NB; i += 256) h[i] = 0;
    __syncthreads();
    int base = tile * TILE;
    int lim = base + TILE; if (lim > E) lim = E;
    for (int i = base + t; i < lim; i += 256) atomicAdd(&h[dst[i] >> BSH], 1);
    __syncthreads();
    for (int i = t; i < NB; i += 256) counts[tile * NB + i] = h[i];
}

// Exclusive scan of counts in BUCKET-MAJOR order (idx = b*NT + t).
__global__ void k_scanA(const int* __restrict__ counts, int NSCAN, int NB, int NT,
                        int* __restrict__ bsum) {
    __shared__ int s[1024];
    int t = threadIdx.x;
    int idx = blockIdx.x * 1024 + t;
    int v = 0;
    if (idx < NSCAN) { int b = idx / NT, tt = idx - b * NT; v = counts[tt * NB + b]; }
    s[t] = v;
    __syncthreads();
    for (int off = 512; off > 0; off >>= 1) {
        if (t < off) s[t] += s[t + off];
        __syncthreads();
    }
    if (t == 0) bsum[blockIdx.x] = s[0];
}

__global__ void k_scanB(int* __restrict__ bsum, int nb) {  // nb <= 1024
    __shared__ int s[1024];
    int t = threadIdx.x;
    int v = (t < nb) ? bsum[t] : 0;
    s[t] = v;
    __syncthreads();
    for (int off = 1; off < 1024; off <<= 1) {
        int a = (t >= off) ? s[t - off] : 0;
        __syncthreads();
        s[t] += a;
        __syncthreads();
    }
    if (t < nb) bsum[t] = s[t] - v;
}

__global__ void k_scanC(const int* __restrict__ counts, int NSCAN, int NB, int NT,
                        const int* __restrict__ bsum, int* __restrict__ tileOffset) {
    __shared__ int s[1024];
    int t = threadIdx.x;
    int idx = blockIdx.x * 1024 + t;
    int v = 0;
    if (idx < NSCAN) { int b = idx / NT, tt = idx - b * NT; v = counts[tt * NB + b]; }
    s[t] = v;
    __syncthreads();
    for (int off = 1; off < 1024; off <<= 1) {
        int a = (t >= off) ? s[t - off] : 0;
        __syncthreads();
        s[t] += a;
        __syncthreads();
    }
    if (idx < NSCAN) tileOffset[idx] = bsum[blockIdx.x] + s[t] - v;  // bucket-major linear
}

// Pass B: scatter packed (local9|src17) into per-(tile,bucket) contiguous runs.
// Tile index is XCD-chunk swizzled (bijective, NT%8 != 0 safe): consecutive
// tiles -> same XCD, so adjacent runs share that XCD's L2 lines.
__global__ void k_tileFill(const int* __restrict__ src, const int* __restrict__ dst,
                           int E, int NB, int NT, const int* __restrict__ tileOffset,
                           int* __restrict__ pairBuf) {
    __shared__ int lcur[BNODES];
    int bid = blockIdx.x;
    int xcd = bid & 7;
    int idx = bid >> 3;
    int q = NT >> 3, r = NT & 7;
    int tile = (xcd < r ? xcd * (q + 1) : r * (q + 1) + (xcd - r) * q) + idx;
    int t = threadIdx.x;
    for (int i = t; i < NB; i += 256) lcur[i] = tileOffset[i * NT + tile];
    __syncthreads();
    int base = tile * TILE;
    int lim = base + TILE; if (lim > E) lim = E;
    for (int i = base + t; i < lim; i += 256) {
        int s = src[i], d = dst[i];
        int b = d >> BSH;
        int pos = atomicAdd(&lcur[b], 1);              // LDS cursor, run is tile-private
        pairBuf[pos] = ((d & (BNODES - 1)) << 17) | s; // src < 2^17
    }
}

// Pass C: per-bucket CSR finish — degi/cursor/dinv + srcSorted placement.
__global__ void k_bucketCSR(const int* __restrict__ pairBuf, const int* __restrict__ tileOffset,
                            int NT, int NB, int E, int n,
                            int* __restrict__ degi, int* __restrict__ cursor,
                            float* __restrict__ dinv, int* __restrict__ srcSorted) {
    __shared__ int cnt[BNODES];
    __shared__ int pref[BNODES];
    int b = blockIdx.x, t = threadIdx.x;
    cnt[t] = 0;
    __syncthreads();
    int bs = tileOffset[b * NT];
    int be = (b + 1 < NB) ? tileOffset[(b + 1) * NT] : E;
    for (int j = bs + t; j < be; j += BNODES) atomicAdd(&cnt[pairBuf[j] >> 17], 1);
    __syncthreads();
    int v = cnt[t];
    pref[t] = v;
    __syncthreads();
    for (int off = 1; off < BNODES; off <<= 1) {
        int a = (t >= off) ? pref[t - off] : 0;
        __syncthreads();
        pref[t] += a;
        __syncthreads();
    }
    int ex = pref[t] - v;                 // exclusive prefix within bucket
    int node = (b << BSH) + t;
    if (node < n) {
        degi[node]   = v;
        cursor[node] = bs + ex;
        dinv[node]   = rsqrtf((float)v + 1.0f);  // +1 self-loop
    }
    __syncthreads();
    cnt[t] = bs + ex;                     // reuse as placement cursors
    __syncthreads();
    for (int j = bs + t; j < be; j += BNODES) {
        int p = pairBuf[j];
        int pos = atomicAdd(&cnt[p >> 17], 1);
        srcSorted[pos] = p & 0x1FFFF;     // writes confined to bucket's ~65KB region
    }
}

// Precompute bf16 B-fragments of W1 for mfma_f32_16x16x32_bf16.
// Wfrag[f=nt*4+ks][lane][j] = bf16( W1[k][col] ), k=ks*32+8*(lane>>4)+j,
// col=nt*16+(lane&15). One tiny block.
__global__ void k_wT(const float* __restrict__ W1, unsigned short* __restrict__ Wfrag) {
    int t = threadIdx.x;
    for (int i = 0; i < 16; ++i) {
        int idx = t + i * 256;            // 4096 elements
        int j = idx & 7;
        int l = (idx >> 3) & 63;
        int f = idx >> 9;                 // 0..7
        int nt = f >> 2, ks = f & 3;
        int k = ks * 32 + ((l >> 4) << 3) + j;
        int col = nt * 16 + (l & 15);
        Wfrag[idx] = f2bf(W1[k * F_HID + col]);
    }
}

// GEMM1 via MFMA: wave = 16 rows x 32 cols, K=128 in 4 steps. No LDS.
// A frag: lane l holds x[row0+(l&15)][8*(l>>4)+j] (fp32->bf16 on the fly).
// D frag (m89): col=lane&15, row=(lane>>4)*4+reg.
__global__ void k_gemm1(const float* __restrict__ x, const unsigned short* __restrict__ Wfrag,
                        const float* __restrict__ dinv, unsigned short* __restrict__ g1b,
                        int n) {
    int wave = threadIdx.x >> 6;          // 0..3
    int lane = threadIdx.x & 63;
    int row0 = (blockIdx.x * 4 + wave) * 16;
    if (row0 >= n) return;                // n % 16 == 0, so full tiles only
    bf16x8 bfr[2][4];
    #pragma unroll
    for (int nt = 0; nt < 2; ++nt)
        #pragma unroll
        for (int ks = 0; ks < 4; ++ks)
            bfr[nt][ks] = *(const bf16x8*)&Wfrag[(((nt << 2) + ks) * 64 + lane) << 3];
    int arow = row0 + (lane & 15);
    const float* xr = x + (size_t)arow * F_IN + ((lane >> 4) << 3);
    f32x4 acc0 = {0.f, 0.f, 0.f, 0.f};
    f32x4 acc1 = {0.f, 0.f, 0.f, 0.f};
    #pragma unroll
    for (int ks = 0; ks < 4; ++ks) {
        float4 lo = *(const float4*)(xr + ks * 32);
        float4 hi = *(const float4*)(xr + ks * 32 + 4);
        bf16x8 a;
        a[0] = (short)f2bf(lo.x); a[1] = (short)f2bf(lo.y);
        a[2] = (short)f2bf(lo.z); a[3] = (short)f2bf(lo.w);
        a[4] = (short)f2bf(hi.x); a[5] = (short)f2bf(hi.y);
        a[6] = (short)f2bf(hi.z); a[7] = (short)f2bf(hi.w);
        acc0 = __builtin_amdgcn_mfma_f32_16x16x32_bf16(a, bfr[0][ks], acc0, 0, 0, 0);
        acc1 = __builtin_amdgcn_mfma_f32_16x16x32_bf16(a, bfr[1][ks], acc1, 0, 0, 0);
    }
    int col = lane & 15;
    #pragma unroll
    for (int rr = 0; rr < 4; ++rr) {
        int orow = row0 + ((lane >> 4) << 2) + rr;
        float di = dinv[orow];
        g1b[(size_t)orow * F_HID + col]      = f2bf(acc0[rr] * di);
        g1b[(size_t)orow * F_HID + col + 16] = f2bf(acc1[rr] * di);
    }
}

// Gather conv1 + ReLU + tiny GEMM2 fused.
// 8 lanes/node (lane c owns 4 bf16 feats as ushort4), 32 nodes/block.
// 4-edge unroll with 4 independent fp32 accumulators.
__global__ void k_gather1l2(const ushort4* __restrict__ g1v, const int* __restrict__ srcSorted,
                            const int* __restrict__ cursor, const int* __restrict__ degi,
                            const float* __restrict__ dinv, const float* __restrict__ b1,
                            const float* __restrict__ W2, unsigned int* __restrict__ g2b,
                            int n) {
    int t = threadIdx.x;
    int c = t & 7;
    int node = blockIdx.x * 32 + (t >> 3);
    if (node >= n) return;
    int start = cursor[node];
    int end = start + degi[node];
    ushort4 sv = g1v[node * 8 + c];   // self-loop init
    float ax = bf2f(sv.x), ay = bf2f(sv.y), az = bf2f(sv.z), aw = bf2f(sv.w);
    float bx = 0.f, by = 0.f, bz = 0.f, bw = 0.f;
    float cx = 0.f, cy = 0.f, cz = 0.f, cw = 0.f;
    float dx = 0.f, dy = 0.f, dz = 0.f, dw = 0.f;
    int j = start;
    for (; j + 4 <= end; j += 4) {
        int s0 = srcSorted[j];
        int s1 = srcSorted[j + 1];
        int s2 = srcSorted[j + 2];
        int s3 = srcSorted[j + 3];
        ushort4 v0 = g1v[s0 * 8 + c];
        ushort4 v1 = g1v[s1 * 8 + c];
        ushort4 v2 = g1v[s2 * 8 + c];
        ushort4 v3 = g1v[s3 * 8 + c];
        ax += bf2f(v0.x); ay += bf2f(v0.y); az += bf2f(v0.z); aw += bf2f(v0.w);
        bx += bf2f(v1.x); by += bf2f(v1.y); bz += bf2f(v1.z); bw += bf2f(v1.w);
        cx += bf2f(v2.x); cy += bf2f(v2.y); cz += bf2f(v2.z); cw += bf2f(v2.w);
        dx += bf2f(v3.x); dy += bf2f(v3.y); dz += bf2f(v3.z); dw += bf2f(v3.w);
    }
    for (; j < end; ++j) {
        ushort4 v0 = g1v[srcSorted[j] * 8 + c];
        ax += bf2f(v0.x); ay += bf2f(v0.y); az += bf2f(v0.z); aw += bf2f(v0.w);
    }
    float accx = (ax + bx) + (cx + dx);
    float accy = (ay + by) + (cy + dy);
    float accz = (az + bz) + (cz + dz);
    float accw = (aw + bw) + (cw + dw);
    float di = dinv[node];
    float4 b4 = ((const float4*)b1)[c];
    float hx = fmaxf(di * accx + b4.x, 0.f);
    float hy = fmaxf(di * accy + b4.y, 0.f);
    float hz = fmaxf(di * accz + b4.z, 0.f);
    float hw = fmaxf(di * accw + b4.w, 0.f);
    float p[F_OUT];
    #pragma unroll
    for (int k = 0; k < F_OUT; ++k) {
        p[k] = hx * W2[(4 * c + 0) * F_OUT + k]
             + hy * W2[(4 * c + 1) * F_OUT + k]
             + hz * W2[(4 * c + 2) * F_OUT + k]
             + hw * W2[(4 * c + 3) * F_OUT + k];
    }
    #pragma unroll
    for (int m = 1; m < 8; m <<= 1) {
        #pragma unroll
        for (int k = 0; k < F_OUT; ++k) p[k] += __shfl_xor(p[k], m, 64);
    }
    if (c == 0) {
        uint4 q;
        q.x = pack2(f2bf(di * p[0]), f2bf(di * p[1]));
        q.y = pack2(f2bf(di * p[2]), f2bf(di * p[3]));
        q.z = pack2(f2bf(di * p[4]), f2bf(di * p[5]));
        q.w = pack2(f2bf(di * p[6]), 0);
        *(uint4*)&g2b[node * 4] = q;      // 16B bf16 row (8 slots, last = 0)
    }
}

// Gather conv2 + bias + log-softmax fused. 8 lanes/node, 4-edge unroll.
// g2 rows are 16B bf16 (L2-resident working set).
__global__ void k_gather2final(const unsigned short* __restrict__ g2b,
                               const int* __restrict__ srcSorted,
                               const int* __restrict__ cursor, const int* __restrict__ degi,
                               const float* __restrict__ dinv, const float* __restrict__ b2,
                               float* __restrict__ out, int n) {
    int t = threadIdx.x;
    int c = t & 7;
    int node = blockIdx.x * 32 + (t >> 3);
    if (node >= n) return;
    int start = cursor[node];
    int end = start + degi[node];
    float a0 = bf2f(g2b[node * 8 + c]);   // self-loop init (pad col = 0)
    float a1 = 0.f, a2 = 0.f, a3 = 0.f;
    int j = start;
    for (; j + 4 <= end; j += 4) {
        int s0 = srcSorted[j];
        int s1 = srcSorted[j + 1];
        int s2 = srcSorted[j + 2];
        int s3 = srcSorted[j + 3];
        a0 += bf2f(g2b[s0 * 8 + c]);
        a1 += bf2f(g2b[s1 * 8 + c]);
        a2 += bf2f(g2b[s2 * 8 + c]);
        a3 += bf2f(g2b[s3 * 8 + c]);
    }
    for (; j < end; ++j) a0 += bf2f(g2b[srcSorted[j] * 8 + c]);
    float acc = (a0 + a1) + (a2 + a3);
    float v = dinv[node] * acc + ((c < F_OUT) ? b2[c] : -1e30f);
    float m = v;
    #pragma unroll
    for (int msk = 1; msk < 8; msk <<= 1) m = fmaxf(m, __shfl_xor(m, msk, 64));
    float ex = __expf(v - m);
    float ssum = ex;
    #pragma unroll
    for (int msk = 1; msk < 8; msk <<= 1) ssum += __shfl_xor(ssum, msk, 64);
    float ls = __logf(ssum) + m;
    if (c < F_OUT) out[node * F_OUT + c] = v - ls;
}

extern "C" void kernel_launch(void* const* d_in, const int* in_sizes, int n_in,
                              void* d_out, int out_size, void* d_ws, size_t ws_size,
                              hipStream_t stream) {
    const float* x  = (const float*)d_in[0];
    const int*   ei = (const int*)d_in[1];
    const float* W1 = (const float*)d_in[2];
    const float* b1 = (const float*)d_in[3];
    const float* W2 = (const float*)d_in[4];
    const float* b2 = (const float*)d_in[5];
    float* out = (float*)d_out;

    int n = in_sizes[0] / F_IN;            // 100000
    int E = in_sizes[1] / 2;               // 3200000
    const int* src = ei;
    const int* dst = ei + E;
    int NB = (n + BNODES - 1) >> BSH;      // 196 buckets
    int NT = (E + TILE - 1) / TILE;        // 782 tiles
    int NSCAN = NB * NT;                   // 153272
    int nsb = (NSCAN + 1023) / 1024;       // 150 scan blocks

    // workspace layout (g1b aliases pairBuf: pairBuf dead after k_bucketCSR)
    int*            degi       = (int*)d_ws;                  // [n]
    int*            cursor     = degi + n;                    // [n]
    float*          dinv       = (float*)(cursor + n);        // [n]
    int*            srcSorted  = (int*)(dinv + n);            // [E]
    int*            pairBuf    = srcSorted + E;               // [E] (reused as g1b)
    unsigned short* g1b        = (unsigned short*)pairBuf;    // [n*32] bf16
    unsigned short* g2b        = (unsigned short*)(pairBuf + E); // [n*8] bf16
    int*            counts     = (int*)(g2b + (size_t)n * 8); // [NSCAN] tile-major
    int*            tileOffset = counts + NSCAN;              // [NSCAN] bucket-major
    int*            bsum       = tileOffset + NSCAN;          // [nsb]
    unsigned short* Wfrag      = (unsigned short*)(bsum + ((nsb + 3) & ~3)); // [4096] bf16, 16B-aligned

    k_wT<<<1, 256, 0, stream>>>(W1, Wfrag);
    k_tileHist<<<NT, 256, 0, stream>>>(dst, E, NB, counts);
    k_scanA<<<nsb, 1024, 0, stream>>>(counts, NSCAN, NB, NT, bsum);
    k_scanB<<<1, 1024, 0, stream>>>(bsum, nsb);
    k_scanC<<<nsb, 1024, 0, stream>>>(counts, NSCAN, NB, NT, bsum, tileOffset);
    k_tileFill<<<NT, 256, 0, stream>>>(src, dst, E, NB, NT, tileOffset, pairBuf);
    k_bucketCSR<<<NB, BNODES, 0, stream>>>(pairBuf, tileOffset, NT, NB, E, n,
                                           degi, cursor, dinv, srcSorted);
    k_gemm1<<<(n + 63) / 64, 256, 0, stream>>>(x, Wfrag, dinv, g1b, n);
    k_gather1l2<<<(n + 31) / 32, 256, 0, stream>>>((const ushort4*)g1b, srcSorted, cursor, degi,
                                                   dinv, b1, W2, (unsigned int*)g2b, n);
    k_gather2final<<<(n + 31) / 32, 256, 0, stream>>>(g2b, srcSorted, cursor, degi, dinv, b2, out, n);
}